// Round 10
// baseline (84.078 us; speedup 1.0000x reference)
//
#include <hip/hip_runtime.h>

constexpr int CH = 128;
constexpr int WW = 48;
constexpr int PP = 2304;           // 48*48
constexpr int NPIX = 4608;         // 2*PP
constexpr int K2 = 169;            // 13x13 window

// workspace layout (floats). Every cell is rewritten each call (no stale state).
constexpr size_t OFF_XT  = 0;                              // [NPIX][CH] pixel-major x
constexpr size_t OFF_RN  = OFF_XT + (size_t)NPIX * CH;     // [NPIX] 1/max(||x||,eps)
constexpr size_t OFF_DF  = OFF_RN + NPIX;                  // [NPIX] df
constexpr size_t OFF_GNP = OFF_DF + NPIX;                  // [288 units][16] GN partials
constexpr size_t OFF_MMP = OFF_GNP + 288 * 16;             // [72 strips][2] min/max partials
constexpr size_t OFF_W1T = OFF_MMP + 144;                  // [32][256][4] packed w1^T
constexpr size_t OFF_W2T = OFF_W1T + 32768;                // [64][128][4] packed w2^T
constexpr size_t WS_FLOATS = OFF_W2T + 32768;

__device__ __forceinline__ int refl(int t) {
    return t < 0 ? -t : (t > 47 ? 94 - t : t);
}

// ===== kernel A: transpose + GN partials | df/rn/minmax partials | pack ====
__global__ __launch_bounds__(256) void kA(const float* __restrict__ x,
                                          const float* __restrict__ w1,
                                          const float* __restrict__ w2,
                                          float* __restrict__ xt,
                                          float* __restrict__ gnp,
                                          float* __restrict__ w1t,
                                          float* __restrict__ w2t,
                                          float* __restrict__ df,
                                          float* __restrict__ rn,
                                          float* __restrict__ mmp) {
    __shared__ union { float t[32][65]; float red[4][64][2]; } sm;
    const int tid = threadIdx.x;
    const int bid = blockIdx.x;
    if (bid < 288) {
        // ---- transpose unit: 64 px x 32 ch; GN partials ----
        const int tile = bid >> 2, q = bid & 3;
        const int p0 = tile * 64;                 // 36 tiles/batch, no straddle
        const int b = p0 / PP, pb = p0 % PP;
        const int pl = tid & 63, cb = tid >> 6;
        const float* xb = x + (size_t)b * CH * PP + (size_t)(q * 32) * PP + pb;
#pragma unroll
        for (int r = 0; r < 8; r++) {
            int c = r * 4 + cb;
            sm.t[c][pl] = xb[(size_t)c * PP + pl];
        }
        __syncthreads();
        {
            const int c4 = tid & 7, pq = tid >> 3;
#pragma unroll
            for (int r = 0; r < 2; r++) {
                int px = r * 32 + pq;
                float4 v = make_float4(sm.t[c4 * 4][px], sm.t[c4 * 4 + 1][px],
                                       sm.t[c4 * 4 + 2][px], sm.t[c4 * 4 + 3][px]);
                ((float4*)(xt + (size_t)(p0 + px) * CH + q * 32))[c4] = v;
            }
        }
        {   // GN partials: local group j -> global g=q*8+j (4 consecutive ch)
            const int j = tid >> 5, part = tid & 31;
            float s = 0.f, sq = 0.f;
#pragma unroll
            for (int pi = 0; pi < 2; pi++) {
                int px = part * 2 + pi;
#pragma unroll
                for (int i = 0; i < 4; i++) {
                    float v = sm.t[j * 4 + i][px];
                    s += v; sq += v * v;
                }
            }
#pragma unroll
            for (int m = 16; m; m >>= 1) { s += __shfl_xor(s, m); sq += __shfl_xor(sq, m); }
            if (part == 0) { gnp[bid * 16 + j * 2] = s; gnp[bid * 16 + j * 2 + 1] = sq; }
        }
    } else if (bid < 360) {
        // ---- df strip: 64 px, from channel-major x; lane=pixel ----
        const int strip = bid - 288;
        const int p0 = strip * 64;                // 36 strips/batch
        const int b = p0 / PP;
        const int wv = tid >> 6, lane = tid & 63;
        const int p = (p0 % PP) + lane;
        const int h = p / WW, w = p % WW;
        float py = 0.5f * h - 0.25f; int y0 = (int)floorf(py); float fy = py - (float)y0;
        float px_ = 0.5f * w - 0.25f; int x0 = (int)floorf(px_); float fx = px_ - (float)x0;
        int y0c = max(y0, 0), y1c = min(y0 + 1, 23);
        int x0c = max(x0, 0), x1c = min(x0 + 1, 23);
        float q00 = 0.25f * (1.f - fy) * (1.f - fx), q01 = 0.25f * (1.f - fy) * fx;
        float q10 = 0.25f * fy * (1.f - fx),        q11 = 0.25f * fy * fx;
        int r0 = (2 * y0c) * WW, r1 = (2 * y0c + 1) * WW;
        int r2 = (2 * y1c) * WW, r3 = (2 * y1c + 1) * WW;
        int ca = 2 * x0c, cb2 = 2 * x1c;
        const float* xc = x + (size_t)b * CH * PP + (size_t)(wv * 32) * PP;
        float ds = 0.f, ss = 0.f;
        for (int c = 0; c < 32; c++) {
            const float* xp = xc + (size_t)c * PP;
            float xv = xp[p];
            float s00 = xp[r0 + ca] + xp[r0 + ca + 1] + xp[r1 + ca] + xp[r1 + ca + 1];
            float s01 = xp[r0 + cb2] + xp[r0 + cb2 + 1] + xp[r1 + cb2] + xp[r1 + cb2 + 1];
            float s10 = xp[r2 + ca] + xp[r2 + ca + 1] + xp[r3 + ca] + xp[r3 + ca + 1];
            float s11 = xp[r2 + cb2] + xp[r2 + cb2 + 1] + xp[r3 + cb2] + xp[r3 + cb2 + 1];
            float up = q00 * s00 + q01 * s01 + q10 * s10 + q11 * s11;
            ds += fabsf(xv - up);
            ss += xv * xv;
        }
        sm.red[wv][lane][0] = ds; sm.red[wv][lane][1] = ss;
        __syncthreads();
        if (wv == 0) {
            float dst = sm.red[0][lane][0] + sm.red[1][lane][0] +
                        sm.red[2][lane][0] + sm.red[3][lane][0];
            float sst = sm.red[0][lane][1] + sm.red[1][lane][1] +
                        sm.red[2][lane][1] + sm.red[3][lane][1];
            df[p0 + lane] = dst;
            rn[p0 + lane] = 1.f / fmaxf(sqrtf(sst), 1e-12f);
            float mn = dst, mx = dst;
#pragma unroll
            for (int m = 32; m; m >>= 1) {
                mn = fminf(mn, __shfl_xor(mn, m));
                mx = fmaxf(mx, __shfl_xor(mx, m));
            }
            if (lane == 0) { mmp[strip * 2] = mn; mmp[strip * 2 + 1] = mx; }
        }
    } else {
        // ---- weight packing: w1 -> w1t4[c4*256+o], w2 -> w2t4[o4*128+c] ----
        int idx = (bid - 360) * 256 + tid;        // 256 blocks x 256 = 65536
        if (idx < 32768) {
            int o = idx >> 7, c = idx & 127;
            w1t[(size_t)((c >> 2) * 256 + o) * 4 + (c & 3)] = w1[idx];
        } else {
            int i2 = idx - 32768;
            int c = i2 >> 8, oo = i2 & 255;
            w2t[(size_t)((oo >> 2) * 128 + c) * 4 + (oo & 3)] = w2[i2];
        }
    }
}

// ===== kernel B: 512 threads / 4 px; wave pair (lo,hi) splits sims K-range;
// ===== lo waves: extraction + pipelined gather + GN + fused FFN ===========
// launch_bounds (512,4): allows 128 VGPR/wave (v9's (512,8) clamped to 32 ->
// load serialization). 1152 blocks -> 4 blocks/CU resident = 32 waves/CU.
__global__ __launch_bounds__(512, 4) void kB(const float* __restrict__ xt,
                                             const float* __restrict__ rn,
                                             const float* __restrict__ df,
                                             const float* __restrict__ mmp,
                                             const float* __restrict__ gnp,
                                             const float* __restrict__ gamma,
                                             const float* __restrict__ beta,
                                             const float* __restrict__ w1t,
                                             const float* __restrict__ w2t,
                                             const float* __restrict__ b1f,
                                             const float* __restrict__ b2f,
                                             float* __restrict__ out) {
    __shared__ union {
        struct { float sims[4][176]; int kl[4][16]; float wl[4][16]; } a;  // 3.3 KB
        struct { float elds[4][128]; float hlds[4][256]; } f;              // 6 KB
    } sm;
    __shared__ float gnbl[32][2];
    __shared__ float mml[2];
    const int tid = threadIdx.x, wv = tid >> 6, lane = tid & 63;
    const int pxw = wv & 3, half = wv >> 2;       // wave pair (lo,hi) per pixel
    const int base = blockIdx.x * 4;              // 1152 blocks, 4 px (4 | PP)
    const int b = base / PP;

    // preamble: per-block GN finalize (wave0) + df min/max (wave1)
    if (tid < 32) {
        const int g = tid, q = g >> 3, j = g & 7;
        float s = 0.f, sq = 0.f;
#pragma unroll 4
        for (int t2 = 0; t2 < 36; t2++) {
            int u = (b * 36 + t2) * 4 + q;
            s += gnp[u * 16 + j * 2];
            sq += gnp[u * 16 + j * 2 + 1];
        }
        float mu = s / 9216.f;
        float var = sq / 9216.f - mu * mu;
        gnbl[g][0] = mu;
        gnbl[g][1] = 1.f / sqrtf(var + 1e-5f);
    } else if (tid >= 64 && tid < 128) {
        int i = tid - 64;
        float mn = 1e30f, mx = -1e30f;
        if (i < 36) { mn = mmp[(b * 36 + i) * 2]; mx = mmp[(b * 36 + i) * 2 + 1]; }
#pragma unroll
        for (int m = 32; m; m >>= 1) {
            mn = fminf(mn, __shfl_xor(mn, m));
            mx = fmaxf(mx, __shfl_xor(mx, m));
        }
        if (i == 0) { mml[0] = mn; mml[1] = mx; }
    }

    const int pix = base + pxw;
    const int p = pix % PP;
    const int h = p / WW, w = p % WW;
    const int bb = b * PP;
    const int g8 = lane >> 3, cl = lane & 7;      // 8 groups of 8 (proven layout)

    // center fragment: ctr[c] = xt[pix][ (c*8+cl)*4 ..+4 )  (full 128B line/row)
    float4 ctr[4];
    const float4* cp = (const float4*)(xt + (size_t)pix * CH) + cl;
#pragma unroll
    for (int c = 0; c < 4; c++) ctr[c] = cp[c * 8];
    const float rnp = rn[pix];
    __syncthreads();                              // gnbl/mml ready

    // sims: this wave covers k in [half*88, half*88+88), 11 batches of 8
    const int kb0 = half * 88;
#pragma unroll 2
    for (int it = 0; it < 11; ++it) {
        const int k = kb0 + it * 8 + g8;
        const int krow = k / 13, kcol = k - krow * 13;
        const int yy = refl(h + krow - 6), xx = refl(w + kcol - 6);
        const int p2 = bb + yy * WW + xx;
        const float4* rp = (const float4*)(xt + (size_t)p2 * CH) + cl;
        float dot = 0.f;
#pragma unroll
        for (int c = 0; c < 4; c++) {
            float4 v = rp[c * 8];
            dot += v.x * ctr[c].x + v.y * ctr[c].y + v.z * ctr[c].z + v.w * ctr[c].w;
        }
        dot += __shfl_xor(dot, 1);
        dot += __shfl_xor(dot, 2);
        dot += __shfl_xor(dot, 4);
        float s = dot * rnp * rn[p2];
        if (cl == 0 && k < K2) sm.a.sims[pxw][k] = s;
    }
    __syncthreads();                              // both halves' sims visible

    float e0 = 0.f, e1 = 0.f;
    if (half == 0) {
        // prefill gather lists (same-wave ordering, no barrier needed)
        if (lane < 16) { sm.a.kl[pxw][lane] = 0; sm.a.wl[pxw][lane] = -1e30f; }
        float s0 = sm.a.sims[pxw][lane];
        float s1 = sm.a.sims[pxw][64 + lane];     // 64+63=127 < 169: all valid
        float s2 = (128 + lane < K2) ? sm.a.sims[pxw][128 + lane] : -1e30f;
        const float dmin = mml[0], dmax = mml[1];
        const float dn = (df[pix] - dmin) / (dmax - dmin + 1e-8f);
        const int cc = 1 + (int)rintf(dn * 15.f);

        // extraction: record top-cc (value desc, index asc) into kl/wl only
        for (int i = 0; i < cc; ++i) {
            float gm = fmaxf(fmaxf(s0, s1), s2);
#pragma unroll
            for (int sft = 1; sft <= 32; sft <<= 1) gm = fmaxf(gm, __shfl_xor(gm, sft));
            unsigned long long m0 = __ballot(s0 == gm);
            unsigned long long m1 = __ballot(s1 == gm);
            unsigned long long m2 = __ballot(s2 == gm);
            int kw = m0 ? (__ffsll(m0) - 1)
                   : m1 ? (64 + __ffsll(m1) - 1)
                        : (128 + __ffsll(m2) - 1);
            bool me = (lane == (kw & 63));
            s0 = (me && kw < 64) ? -1e30f : s0;
            s1 = (me && kw >= 64 && kw < 128) ? -1e30f : s1;
            s2 = (me && kw >= 128) ? -1e30f : s2;
            if (lane == 0) { sm.a.kl[pxw][i] = kw; sm.a.wl[pxw][i] = gm; }
        }

        // pipelined gather: 16 unrolled iterations, all loads in flight.
        // i >= cc: wl = -1e30 -> expf = 0 exactly; kl = 0 -> harmless load.
        float wsum = 0.f, ax = 0.f, ay = 0.f;
#pragma unroll
        for (int i = 0; i < 16; ++i) {
            const int kw = sm.a.kl[pxw][i];
            const float sv = sm.a.wl[pxw][i];
            const float wt = expf(sv);
            const int krow = kw / 13, kcol = kw - krow * 13;
            const int p2 = bb + refl(h + krow - 6) * WW + refl(w + kcol - 6);
            float2 v = ((const float2*)(xt + (size_t)p2 * CH))[lane];
            wsum += wt; ax += wt * v.x; ay += wt * v.y;
        }
        const float invw = 1.f / wsum;

        // GroupNorm + residual -> enhanced (registers)
        float2 xv = ((const float2*)(xt + (size_t)pix * CH))[lane];
        const int c0 = lane * 2, grp = lane >> 1;
        const float mu = gnbl[grp][0], rstd = gnbl[grp][1];
        e0 = ax * invw + (xv.x - mu) * rstd * gamma[c0] + beta[c0];
        e1 = ay * invw + (xv.y - mu) * rstd * gamma[c0 + 1] + beta[c0 + 1];
    }

    __syncthreads();                              // all reads of sm.a done
    if (half == 0) ((float2*)sm.f.elds[pxw])[lane] = make_float2(e0, e1);
    __syncthreads();

    // FFN stage 1 (tid<256): thread = output o; w1t4 coalesced, elds broadcast
    if (tid < 256) {
        float acc4[4] = {0.f, 0.f, 0.f, 0.f};
        const float4* wp = ((const float4*)w1t) + tid;
        for (int c4 = 0; c4 < 32; c4++) {
            float4 wv4 = wp[c4 * 256];
#pragma unroll
            for (int px = 0; px < 4; px++) {
                float4 ev = *(const float4*)&sm.f.elds[px][c4 * 4];
                acc4[px] += wv4.x * ev.x + wv4.y * ev.y + wv4.z * ev.z + wv4.w * ev.w;
            }
        }
        float bv = b1f[tid];
#pragma unroll
        for (int px = 0; px < 4; px++)
            sm.f.hlds[px][tid] = fmaxf(acc4[px] + bv, 0.f);
    }
    __syncthreads();
    // FFN stage 2 + residual (tid<256): thread = (c, hf); w2t4 coalesced
    if (tid < 256) {
        const int c = tid & 127, hf = tid >> 7;
        const int px0 = hf * 2;
        float acc2[2] = {0.f, 0.f};
        const float4* wp2 = ((const float4*)w2t) + c;
        for (int o4 = 0; o4 < 64; o4++) {
            float4 wv4 = wp2[o4 * 128];
#pragma unroll
            for (int j = 0; j < 2; j++) {
                float4 hv = *(const float4*)&sm.f.hlds[px0 + j][o4 * 4];
                acc2[j] += wv4.x * hv.x + wv4.y * hv.y + wv4.z * hv.z + wv4.w * hv.w;
            }
        }
        float bv = b2f[c];
        float2 o2;
        o2.x = sm.f.elds[px0 + 0][c] + acc2[0] + bv;
        o2.y = sm.f.elds[px0 + 1][c] + acc2[1] + bv;
        *(float2*)(out + ((size_t)(b * CH + c)) * PP + (base % PP) + px0) = o2;
    }
}

extern "C" void kernel_launch(void* const* d_in, const int* in_sizes, int n_in,
                              void* d_out, int out_size, void* d_ws, size_t ws_size,
                              hipStream_t stream) {
    (void)in_sizes; (void)n_in; (void)out_size;
    if (ws_size < WS_FLOATS * sizeof(float)) return;  // would corrupt; fail visibly

    const float* x     = (const float*)d_in[0];
    const float* gamma = (const float*)d_in[1];
    const float* beta  = (const float*)d_in[2];
    const float* w1    = (const float*)d_in[3];
    const float* b1    = (const float*)d_in[4];
    const float* w2    = (const float*)d_in[5];
    const float* b2    = (const float*)d_in[6];
    float* ws = (float*)d_ws;
    float* xt  = ws + OFF_XT;
    float* rn  = ws + OFF_RN;
    float* df  = ws + OFF_DF;
    float* gnp = ws + OFF_GNP;
    float* mmp = ws + OFF_MMP;
    float* w1t = ws + OFF_W1T;
    float* w2t = ws + OFF_W2T;
    float* out = (float*)d_out;

    hipLaunchKernelGGL(kA, dim3(616),  dim3(256), 0, stream,
                       x, w1, w2, xt, gnp, w1t, w2t, df, rn, mmp);
    hipLaunchKernelGGL(kB, dim3(1152), dim3(512), 0, stream,
                       xt, rn, df, mmp, gnp, gamma, beta, w1t, w2t, b1, b2, out);
}

// Round 11
// 70.146 us; speedup vs baseline: 1.1986x; 1.1986x over previous
//
#include <hip/hip_runtime.h>

constexpr int CH = 128;
constexpr int WW = 48;
constexpr int PP = 2304;           // 48*48
constexpr int NPIX = 4608;         // 2*PP
constexpr int K2 = 169;            // 13x13 window

// workspace layout (floats). Every cell read is rewritten each call.
constexpr size_t OFF_XT   = 0;                             // [NPIX][CH] pixel-major x
constexpr size_t OFF_SIMS = OFF_XT + (size_t)NPIX * CH;    // [NPIX][176] sims
constexpr size_t OFF_RN   = OFF_SIMS + (size_t)NPIX * 176; // [NPIX] 1/max(||x||,eps)
constexpr size_t OFF_DF   = OFF_RN + NPIX;                 // [NPIX] df
constexpr size_t OFF_GNP  = OFF_DF + NPIX;                 // [288 units][16] GN partials
constexpr size_t OFF_MMP  = OFF_GNP + 288 * 16;            // [72 strips][2] min/max partials
constexpr size_t OFF_W1T  = OFF_MMP + 144;                 // [32][256][4] packed w1^T
constexpr size_t OFF_W2T  = OFF_W1T + 32768;               // [64][128][4] packed w2^T
constexpr size_t WS_FLOATS = OFF_W2T + 32768;

__device__ __forceinline__ int refl(int t) {
    return t < 0 ? -t : (t > 47 ? 94 - t : t);
}

// ===== kernel A: transpose + GN partials | df/rn/minmax partials | pack ====
__global__ __launch_bounds__(256) void kA(const float* __restrict__ x,
                                          const float* __restrict__ w1,
                                          const float* __restrict__ w2,
                                          float* __restrict__ xt,
                                          float* __restrict__ gnp,
                                          float* __restrict__ w1t,
                                          float* __restrict__ w2t,
                                          float* __restrict__ df,
                                          float* __restrict__ rn,
                                          float* __restrict__ mmp) {
    __shared__ union { float t[32][65]; float red[4][64][2]; } sm;
    const int tid = threadIdx.x;
    const int bid = blockIdx.x;
    if (bid < 288) {
        // ---- transpose unit: 64 px x 32 ch; GN partials ----
        const int tile = bid >> 2, q = bid & 3;
        const int p0 = tile * 64;                 // 36 tiles/batch, no straddle
        const int b = p0 / PP, pb = p0 % PP;
        const int pl = tid & 63, cb = tid >> 6;
        const float* xb = x + (size_t)b * CH * PP + (size_t)(q * 32) * PP + pb;
#pragma unroll
        for (int r = 0; r < 8; r++) {
            int c = r * 4 + cb;
            sm.t[c][pl] = xb[(size_t)c * PP + pl];
        }
        __syncthreads();
        {
            const int c4 = tid & 7, pq = tid >> 3;
#pragma unroll
            for (int r = 0; r < 2; r++) {
                int px = r * 32 + pq;
                float4 v = make_float4(sm.t[c4 * 4][px], sm.t[c4 * 4 + 1][px],
                                       sm.t[c4 * 4 + 2][px], sm.t[c4 * 4 + 3][px]);
                ((float4*)(xt + (size_t)(p0 + px) * CH + q * 32))[c4] = v;
            }
        }
        {   // GN partials: local group j -> global g=q*8+j (4 consecutive ch)
            const int j = tid >> 5, part = tid & 31;
            float s = 0.f, sq = 0.f;
#pragma unroll
            for (int pi = 0; pi < 2; pi++) {
                int px = part * 2 + pi;
#pragma unroll
                for (int i = 0; i < 4; i++) {
                    float v = sm.t[j * 4 + i][px];
                    s += v; sq += v * v;
                }
            }
#pragma unroll
            for (int m = 16; m; m >>= 1) { s += __shfl_xor(s, m); sq += __shfl_xor(sq, m); }
            if (part == 0) { gnp[bid * 16 + j * 2] = s; gnp[bid * 16 + j * 2 + 1] = sq; }
        }
    } else if (bid < 360) {
        // ---- df strip: 64 px, from channel-major x; lane=pixel ----
        const int strip = bid - 288;
        const int p0 = strip * 64;                // 36 strips/batch
        const int b = p0 / PP;
        const int wv = tid >> 6, lane = tid & 63;
        const int p = (p0 % PP) + lane;
        const int h = p / WW, w = p % WW;
        float py = 0.5f * h - 0.25f; int y0 = (int)floorf(py); float fy = py - (float)y0;
        float px_ = 0.5f * w - 0.25f; int x0 = (int)floorf(px_); float fx = px_ - (float)x0;
        int y0c = max(y0, 0), y1c = min(y0 + 1, 23);
        int x0c = max(x0, 0), x1c = min(x0 + 1, 23);
        float q00 = 0.25f * (1.f - fy) * (1.f - fx), q01 = 0.25f * (1.f - fy) * fx;
        float q10 = 0.25f * fy * (1.f - fx),        q11 = 0.25f * fy * fx;
        int r0 = (2 * y0c) * WW, r1 = (2 * y0c + 1) * WW;
        int r2 = (2 * y1c) * WW, r3 = (2 * y1c + 1) * WW;
        int ca = 2 * x0c, cb2 = 2 * x1c;
        const float* xc = x + (size_t)b * CH * PP + (size_t)(wv * 32) * PP;
        float ds = 0.f, ss = 0.f;
        for (int c = 0; c < 32; c++) {
            const float* xp = xc + (size_t)c * PP;
            float xv = xp[p];
            float s00 = xp[r0 + ca] + xp[r0 + ca + 1] + xp[r1 + ca] + xp[r1 + ca + 1];
            float s01 = xp[r0 + cb2] + xp[r0 + cb2 + 1] + xp[r1 + cb2] + xp[r1 + cb2 + 1];
            float s10 = xp[r2 + ca] + xp[r2 + ca + 1] + xp[r3 + ca] + xp[r3 + ca + 1];
            float s11 = xp[r2 + cb2] + xp[r2 + cb2 + 1] + xp[r3 + cb2] + xp[r3 + cb2 + 1];
            float up = q00 * s00 + q01 * s01 + q10 * s10 + q11 * s11;
            ds += fabsf(xv - up);
            ss += xv * xv;
        }
        sm.red[wv][lane][0] = ds; sm.red[wv][lane][1] = ss;
        __syncthreads();
        if (wv == 0) {
            float dst = sm.red[0][lane][0] + sm.red[1][lane][0] +
                        sm.red[2][lane][0] + sm.red[3][lane][0];
            float sst = sm.red[0][lane][1] + sm.red[1][lane][1] +
                        sm.red[2][lane][1] + sm.red[3][lane][1];
            df[p0 + lane] = dst;
            rn[p0 + lane] = 1.f / fmaxf(sqrtf(sst), 1e-12f);
            float mn = dst, mx = dst;
#pragma unroll
            for (int m = 32; m; m >>= 1) {
                mn = fminf(mn, __shfl_xor(mn, m));
                mx = fmaxf(mx, __shfl_xor(mx, m));
            }
            if (lane == 0) { mmp[strip * 2] = mn; mmp[strip * 2 + 1] = mx; }
        }
    } else {
        // ---- weight packing: w1 -> w1t4[c4*256+o], w2 -> w2t4[o4*128+c] ----
        int idx = (bid - 360) * 256 + tid;        // 256 blocks x 256 = 65536
        if (idx < 32768) {
            int o = idx >> 7, c = idx & 127;
            w1t[(size_t)((c >> 2) * 256 + o) * 4 + (c & 3)] = w1[idx];
        } else {
            int i2 = idx - 32768;
            int c = i2 >> 8, oo = i2 & 255;
            w2t[(size_t)((oo >> 2) * 128 + c) * 4 + (oo & 3)] = w2[i2];
        }
    }
}

// ===== kernel S: sims only — barrier-free, no LDS, 2 independent waves/px =
// wave = (pixel, k-half). 8-groups-of-8 layout: group g8 = offset, lane cl
// owns a full 128B line slice; 8-lane shuffle reduce; reduced lanes store
// one contiguous 32B chunk of sims[pix][.] per iteration.
__global__ __launch_bounds__(256) void kS(const float* __restrict__ xt,
                                          const float* __restrict__ rn,
                                          float* __restrict__ simsw) {
    const int tid = threadIdx.x, wv = tid >> 6, lane = tid & 63;
    const int pix = blockIdx.x * 2 + (wv & 1);    // 2304 blocks * 2 px
    const int half = wv >> 1;                     // k in [half*88, half*88+88)
    const int p = pix % PP;
    const int h = p / WW, w = p % WW;
    const int bb = (pix / PP) * PP;
    const int g8 = lane >> 3, cl = lane & 7;

    float4 ctr[4];
    const float4* cp = (const float4*)(xt + (size_t)pix * CH) + cl;
#pragma unroll
    for (int c = 0; c < 4; c++) ctr[c] = cp[c * 8];
    const float rnp = rn[pix];

    const int kb0 = half * 88;
#pragma unroll 2
    for (int it = 0; it < 11; ++it) {
        const int k = kb0 + it * 8 + g8;
        const int krow = k / 13, kcol = k - krow * 13;
        const int yy = refl(h + krow - 6), xx = refl(w + kcol - 6);
        const int p2 = bb + yy * WW + xx;
        const float4* rp = (const float4*)(xt + (size_t)p2 * CH) + cl;
        float dot = 0.f;
#pragma unroll
        for (int c = 0; c < 4; c++) {
            float4 v = rp[c * 8];
            dot += v.x * ctr[c].x + v.y * ctr[c].y + v.z * ctr[c].z + v.w * ctr[c].w;
        }
        dot += __shfl_xor(dot, 1);
        dot += __shfl_xor(dot, 2);
        dot += __shfl_xor(dot, 4);
        if (cl == 0 && k < K2)
            simsw[(size_t)pix * 176 + k] = dot * rnp * rn[p2];
    }
}

// ===== kernel B: preamble + extraction (sims from L2) + pipelined gather
// ===== + GN + fused FFN — v7 structure minus the sims compute =============
__global__ __launch_bounds__(256, 2) void kB(const float* __restrict__ xt,
                                             const float* __restrict__ simsw,
                                             const float* __restrict__ rn,
                                             const float* __restrict__ df,
                                             const float* __restrict__ mmp,
                                             const float* __restrict__ gnp,
                                             const float* __restrict__ gamma,
                                             const float* __restrict__ beta,
                                             const float* __restrict__ w1t,
                                             const float* __restrict__ w2t,
                                             const float* __restrict__ b1f,
                                             const float* __restrict__ b2f,
                                             float* __restrict__ out) {
    __shared__ union {
        struct { int kl[4][16]; float wl[4][16]; } a;              // 512 B
        struct { float elds[4][128]; float hlds[4][256]; } f;      // 6 KB
    } sm;
    __shared__ float gnbl[32][2];
    __shared__ float mml[2];
    const int tid = threadIdx.x, wv = tid >> 6, lane = tid & 63;
    const int base = blockIdx.x * 4;              // 1152 blocks, 4 px (4 | PP)
    const int b = base / PP;

    // preamble: per-block GN finalize (wave0) + df min/max (wave1)
    if (tid < 32) {
        const int g = tid, q = g >> 3, j = g & 7;
        float s = 0.f, sq = 0.f;
#pragma unroll 4
        for (int t2 = 0; t2 < 36; t2++) {
            int u = (b * 36 + t2) * 4 + q;
            s += gnp[u * 16 + j * 2];
            sq += gnp[u * 16 + j * 2 + 1];
        }
        float mu = s / 9216.f;
        float var = sq / 9216.f - mu * mu;
        gnbl[g][0] = mu;
        gnbl[g][1] = 1.f / sqrtf(var + 1e-5f);
    } else if (tid >= 64 && tid < 128) {
        int i = tid - 64;
        float mn = 1e30f, mx = -1e30f;
        if (i < 36) { mn = mmp[(b * 36 + i) * 2]; mx = mmp[(b * 36 + i) * 2 + 1]; }
#pragma unroll
        for (int m = 32; m; m >>= 1) {
            mn = fminf(mn, __shfl_xor(mn, m));
            mx = fmaxf(mx, __shfl_xor(mx, m));
        }
        if (i == 0) { mml[0] = mn; mml[1] = mx; }
    }

    const int pix = base + wv;
    const int p = pix % PP;
    const int h = p / WW, w = p % WW;
    const int bb = b * PP;

    // own slots: coalesced 256B rows from simsw (L2-resident)
    const float* srow = simsw + (size_t)pix * 176;
    float s0 = srow[lane];
    float s1 = srow[64 + lane];                   // 64+63=127 < 169: all valid
    float s2 = (128 + lane < K2) ? srow[128 + lane] : -1e30f;

    // prefill gather lists (same-wave ordering, no barrier needed)
    if (lane < 16) { sm.a.kl[wv][lane] = 0; sm.a.wl[wv][lane] = -1e30f; }
    __syncthreads();                              // gnbl/mml ready

    const float dmin = mml[0], dmax = mml[1];
    const float dn = (df[pix] - dmin) / (dmax - dmin + 1e-8f);
    const int cc = 1 + (int)rintf(dn * 15.f);

    // extraction: record top-cc (value desc, index asc) into kl/wl only
    for (int i = 0; i < cc; ++i) {
        float gm = fmaxf(fmaxf(s0, s1), s2);
#pragma unroll
        for (int sft = 1; sft <= 32; sft <<= 1) gm = fmaxf(gm, __shfl_xor(gm, sft));
        unsigned long long m0 = __ballot(s0 == gm);
        unsigned long long m1 = __ballot(s1 == gm);
        unsigned long long m2 = __ballot(s2 == gm);
        int kw = m0 ? (__ffsll(m0) - 1)
               : m1 ? (64 + __ffsll(m1) - 1)
                    : (128 + __ffsll(m2) - 1);
        bool me = (lane == (kw & 63));
        s0 = (me && kw < 64) ? -1e30f : s0;
        s1 = (me && kw >= 64 && kw < 128) ? -1e30f : s1;
        s2 = (me && kw >= 128) ? -1e30f : s2;
        if (lane == 0) { sm.a.kl[wv][i] = kw; sm.a.wl[wv][i] = gm; }
    }

    // pipelined gather: 16 unrolled iterations, all loads in flight.
    // i >= cc: wl = -1e30 -> expf = 0 exactly; kl = 0 -> harmless load.
    float wsum = 0.f, ax = 0.f, ay = 0.f;
#pragma unroll
    for (int i = 0; i < 16; ++i) {
        const int kw = sm.a.kl[wv][i];
        const float sv = sm.a.wl[wv][i];
        const float wt = expf(sv);
        const int krow = kw / 13, kcol = kw - krow * 13;
        const int p2 = bb + refl(h + krow - 6) * WW + refl(w + kcol - 6);
        float2 v = ((const float2*)(xt + (size_t)p2 * CH))[lane];
        wsum += wt; ax += wt * v.x; ay += wt * v.y;
    }
    const float invw = 1.f / wsum;

    // GroupNorm + residual -> enhanced (registers)
    float2 xv = ((const float2*)(xt + (size_t)pix * CH))[lane];
    const int c0 = lane * 2, grp = lane >> 1;
    const float mu = gnbl[grp][0], rstd = gnbl[grp][1];
    float e0 = ax * invw + (xv.x - mu) * rstd * gamma[c0] + beta[c0];
    float e1 = ay * invw + (xv.y - mu) * rstd * gamma[c0 + 1] + beta[c0 + 1];

    __syncthreads();                              // all reads of sm.a done
    ((float2*)sm.f.elds[wv])[lane] = make_float2(e0, e1);
    __syncthreads();

    // FFN stage 1: thread = output o; w1t4 coalesced, elds LDS broadcast
    {
        float acc4[4] = {0.f, 0.f, 0.f, 0.f};
        const float4* wp = ((const float4*)w1t) + tid;
        for (int c4 = 0; c4 < 32; c4++) {
            float4 wv4 = wp[c4 * 256];
#pragma unroll
            for (int px = 0; px < 4; px++) {
                float4 ev = *(const float4*)&sm.f.elds[px][c4 * 4];
                acc4[px] += wv4.x * ev.x + wv4.y * ev.y + wv4.z * ev.z + wv4.w * ev.w;
            }
        }
        float bv = b1f[tid];
#pragma unroll
        for (int px = 0; px < 4; px++)
            sm.f.hlds[px][tid] = fmaxf(acc4[px] + bv, 0.f);
    }
    __syncthreads();
    // FFN stage 2 + residual: thread = (c, hf); w2t4 coalesced
    {
        const int c = tid & 127, hf = tid >> 7;
        const int px0 = hf * 2;
        float acc2[2] = {0.f, 0.f};
        const float4* wp2 = ((const float4*)w2t) + c;
        for (int o4 = 0; o4 < 64; o4++) {
            float4 wv4 = wp2[o4 * 128];
#pragma unroll
            for (int j = 0; j < 2; j++) {
                float4 hv = *(const float4*)&sm.f.hlds[px0 + j][o4 * 4];
                acc2[j] += wv4.x * hv.x + wv4.y * hv.y + wv4.z * hv.z + wv4.w * hv.w;
            }
        }
        float bv = b2f[c];
        float2 o2;
        o2.x = sm.f.elds[px0 + 0][c] + acc2[0] + bv;
        o2.y = sm.f.elds[px0 + 1][c] + acc2[1] + bv;
        *(float2*)(out + ((size_t)(b * CH + c)) * PP + (base % PP) + px0) = o2;
    }
}

extern "C" void kernel_launch(void* const* d_in, const int* in_sizes, int n_in,
                              void* d_out, int out_size, void* d_ws, size_t ws_size,
                              hipStream_t stream) {
    (void)in_sizes; (void)n_in; (void)out_size;
    if (ws_size < WS_FLOATS * sizeof(float)) return;  // would corrupt; fail visibly

    const float* x     = (const float*)d_in[0];
    const float* gamma = (const float*)d_in[1];
    const float* beta  = (const float*)d_in[2];
    const float* w1    = (const float*)d_in[3];
    const float* b1    = (const float*)d_in[4];
    const float* w2    = (const float*)d_in[5];
    const float* b2    = (const float*)d_in[6];
    float* ws = (float*)d_ws;
    float* xt    = ws + OFF_XT;
    float* simsw = ws + OFF_SIMS;
    float* rn    = ws + OFF_RN;
    float* df    = ws + OFF_DF;
    float* gnp   = ws + OFF_GNP;
    float* mmp   = ws + OFF_MMP;
    float* w1t   = ws + OFF_W1T;
    float* w2t   = ws + OFF_W2T;
    float* out   = (float*)d_out;

    hipLaunchKernelGGL(kA, dim3(616),  dim3(256), 0, stream,
                       x, w1, w2, xt, gnp, w1t, w2t, df, rn, mmp);
    hipLaunchKernelGGL(kS, dim3(2304), dim3(256), 0, stream, xt, rn, simsw);
    hipLaunchKernelGGL(kB, dim3(1152), dim3(256), 0, stream,
                       xt, simsw, rn, df, mmp, gnp, gamma, beta, w1t, w2t, b1, b2, out);
}

// Round 12
// 63.444 us; speedup vs baseline: 1.3252x; 1.1056x over previous
//
#include <hip/hip_runtime.h>

constexpr int CH = 128;
constexpr int WW = 48;
constexpr int PP = 2304;           // 48*48
constexpr int NPIX = 4608;         // 2*PP
constexpr int K2 = 169;            // 13x13 window

// workspace layout (floats). Every cell read is rewritten each call.
constexpr size_t OFF_XT  = 0;                              // [NPIX][CH] pixel-major x
constexpr size_t OFF_RN  = OFF_XT + (size_t)NPIX * CH;     // [NPIX] 1/max(||x||,eps)
constexpr size_t OFF_DF  = OFF_RN + NPIX;                  // [NPIX] df
constexpr size_t OFF_GNP = OFF_DF + NPIX;                  // [288 units][16] GN partials
constexpr size_t OFF_MMP = OFF_GNP + 288 * 16;             // [72 strips][2] min/max partials
constexpr size_t OFF_W1T = OFF_MMP + 144;                  // [32][256][4] packed w1^T
constexpr size_t OFF_W2T = OFF_W1T + 32768;                // [64][128][4] packed w2^T
constexpr size_t WS_FLOATS = OFF_W2T + 32768;

__device__ __forceinline__ int refl(int t) {
    return t < 0 ? -t : (t > 47 ? 94 - t : t);
}

// ===== kernel A: transpose + GN partials | df/rn/minmax partials | pack ====
__global__ __launch_bounds__(256) void kA(const float* __restrict__ x,
                                          const float* __restrict__ w1,
                                          const float* __restrict__ w2,
                                          float* __restrict__ xt,
                                          float* __restrict__ gnp,
                                          float* __restrict__ w1t,
                                          float* __restrict__ w2t,
                                          float* __restrict__ df,
                                          float* __restrict__ rn,
                                          float* __restrict__ mmp) {
    __shared__ union { float t[32][65]; float red[4][64][2]; } sm;
    const int tid = threadIdx.x;
    const int bid = blockIdx.x;
    if (bid < 288) {
        // ---- transpose unit: 64 px x 32 ch; GN partials ----
        const int tile = bid >> 2, q = bid & 3;
        const int p0 = tile * 64;                 // 36 tiles/batch, no straddle
        const int b = p0 / PP, pb = p0 % PP;
        const int pl = tid & 63, cb = tid >> 6;
        const float* xb = x + (size_t)b * CH * PP + (size_t)(q * 32) * PP + pb;
#pragma unroll
        for (int r = 0; r < 8; r++) {
            int c = r * 4 + cb;
            sm.t[c][pl] = xb[(size_t)c * PP + pl];
        }
        __syncthreads();
        {
            const int c4 = tid & 7, pq = tid >> 3;
#pragma unroll
            for (int r = 0; r < 2; r++) {
                int px = r * 32 + pq;
                float4 v = make_float4(sm.t[c4 * 4][px], sm.t[c4 * 4 + 1][px],
                                       sm.t[c4 * 4 + 2][px], sm.t[c4 * 4 + 3][px]);
                ((float4*)(xt + (size_t)(p0 + px) * CH + q * 32))[c4] = v;
            }
        }
        {   // GN partials: local group j -> global g=q*8+j (4 consecutive ch)
            const int j = tid >> 5, part = tid & 31;
            float s = 0.f, sq = 0.f;
#pragma unroll
            for (int pi = 0; pi < 2; pi++) {
                int px = part * 2 + pi;
#pragma unroll
                for (int i = 0; i < 4; i++) {
                    float v = sm.t[j * 4 + i][px];
                    s += v; sq += v * v;
                }
            }
#pragma unroll
            for (int m = 16; m; m >>= 1) { s += __shfl_xor(s, m); sq += __shfl_xor(sq, m); }
            if (part == 0) { gnp[bid * 16 + j * 2] = s; gnp[bid * 16 + j * 2 + 1] = sq; }
        }
    } else if (bid < 360) {
        // ---- df strip: 64 px, from channel-major x; lane=pixel ----
        const int strip = bid - 288;
        const int p0 = strip * 64;                // 36 strips/batch
        const int b = p0 / PP;
        const int wv = tid >> 6, lane = tid & 63;
        const int p = (p0 % PP) + lane;
        const int h = p / WW, w = p % WW;
        float py = 0.5f * h - 0.25f; int y0 = (int)floorf(py); float fy = py - (float)y0;
        float px_ = 0.5f * w - 0.25f; int x0 = (int)floorf(px_); float fx = px_ - (float)x0;
        int y0c = max(y0, 0), y1c = min(y0 + 1, 23);
        int x0c = max(x0, 0), x1c = min(x0 + 1, 23);
        float q00 = 0.25f * (1.f - fy) * (1.f - fx), q01 = 0.25f * (1.f - fy) * fx;
        float q10 = 0.25f * fy * (1.f - fx),        q11 = 0.25f * fy * fx;
        int r0 = (2 * y0c) * WW, r1 = (2 * y0c + 1) * WW;
        int r2 = (2 * y1c) * WW, r3 = (2 * y1c + 1) * WW;
        int ca = 2 * x0c, cb2 = 2 * x1c;
        const float* xc = x + (size_t)b * CH * PP + (size_t)(wv * 32) * PP;
        float ds = 0.f, ss = 0.f;
        for (int c = 0; c < 32; c++) {
            const float* xp = xc + (size_t)c * PP;
            float xv = xp[p];
            float s00 = xp[r0 + ca] + xp[r0 + ca + 1] + xp[r1 + ca] + xp[r1 + ca + 1];
            float s01 = xp[r0 + cb2] + xp[r0 + cb2 + 1] + xp[r1 + cb2] + xp[r1 + cb2 + 1];
            float s10 = xp[r2 + ca] + xp[r2 + ca + 1] + xp[r3 + ca] + xp[r3 + ca + 1];
            float s11 = xp[r2 + cb2] + xp[r2 + cb2 + 1] + xp[r3 + cb2] + xp[r3 + cb2 + 1];
            float up = q00 * s00 + q01 * s01 + q10 * s10 + q11 * s11;
            ds += fabsf(xv - up);
            ss += xv * xv;
        }
        sm.red[wv][lane][0] = ds; sm.red[wv][lane][1] = ss;
        __syncthreads();
        if (wv == 0) {
            float dst = sm.red[0][lane][0] + sm.red[1][lane][0] +
                        sm.red[2][lane][0] + sm.red[3][lane][0];
            float sst = sm.red[0][lane][1] + sm.red[1][lane][1] +
                        sm.red[2][lane][1] + sm.red[3][lane][1];
            df[p0 + lane] = dst;
            rn[p0 + lane] = 1.f / fmaxf(sqrtf(sst), 1e-12f);
            float mn = dst, mx = dst;
#pragma unroll
            for (int m = 32; m; m >>= 1) {
                mn = fminf(mn, __shfl_xor(mn, m));
                mx = fmaxf(mx, __shfl_xor(mx, m));
            }
            if (lane == 0) { mmp[strip * 2] = mn; mmp[strip * 2 + 1] = mx; }
        }
    } else {
        // ---- weight packing: w1 -> w1t4[c4*256+o], w2 -> w2t4[o4*128+c] ----
        int idx = (bid - 360) * 256 + tid;        // 256 blocks x 256 = 65536
        if (idx < 32768) {
            int o = idx >> 7, c = idx & 127;
            w1t[(size_t)((c >> 2) * 256 + o) * 4 + (c & 3)] = w1[idx];
        } else {
            int i2 = idx - 32768;
            int c = i2 >> 8, oo = i2 & 255;
            w2t[(size_t)((oo >> 2) * 128 + c) * 4 + (oo & 3)] = w2[i2];
        }
    }
}

// ===== kernel B (v12): v7 structure + deep-ILP sims (2-wide interleave),
// ===== decoupled extraction, 16-wide gather, 8-deep FFN weight preload ====
__global__ __launch_bounds__(256, 2) void kB(const float* __restrict__ xt,
                                             const float* __restrict__ rn,
                                             const float* __restrict__ df,
                                             const float* __restrict__ mmp,
                                             const float* __restrict__ gnp,
                                             const float* __restrict__ gamma,
                                             const float* __restrict__ beta,
                                             const float* __restrict__ w1t,
                                             const float* __restrict__ w2t,
                                             const float* __restrict__ b1f,
                                             const float* __restrict__ b2f,
                                             float* __restrict__ out) {
    __shared__ union {
        struct { float sims[4][176]; int kl[4][16]; float wl[4][16]; } a;  // 3.3 KB
        struct { float elds[4][128]; float hlds[4][256]; } f;              // 6 KB
    } sm;
    __shared__ float gnbl[32][2];
    __shared__ float mml[2];
    const int tid = threadIdx.x, wv = tid >> 6, lane = tid & 63;
    const int base = blockIdx.x * 4;              // 1152 blocks, 4 px (4 | PP)
    const int b = base / PP;

    // preamble: per-block GN finalize (wave0) + df min/max (wave1)
    if (tid < 32) {
        const int g = tid, q = g >> 3, j = g & 7;
        float s = 0.f, sq = 0.f;
#pragma unroll 4
        for (int t2 = 0; t2 < 36; t2++) {
            int u = (b * 36 + t2) * 4 + q;
            s += gnp[u * 16 + j * 2];
            sq += gnp[u * 16 + j * 2 + 1];
        }
        float mu = s / 9216.f;
        float var = sq / 9216.f - mu * mu;
        gnbl[g][0] = mu;
        gnbl[g][1] = 1.f / sqrtf(var + 1e-5f);
    } else if (tid >= 64 && tid < 128) {
        int i = tid - 64;
        float mn = 1e30f, mx = -1e30f;
        if (i < 36) { mn = mmp[(b * 36 + i) * 2]; mx = mmp[(b * 36 + i) * 2 + 1]; }
#pragma unroll
        for (int m = 32; m; m >>= 1) {
            mn = fminf(mn, __shfl_xor(mn, m));
            mx = fmaxf(mx, __shfl_xor(mx, m));
        }
        if (i == 0) { mml[0] = mn; mml[1] = mx; }
    }

    const int pix = base + wv;
    const int p = pix % PP;
    const int h = p / WW, w = p % WW;
    const int bb = b * PP;
    const int g8 = lane >> 3, cl = lane & 7;      // 8 groups of 8 (proven layout)

    // center fragment: ctr[c] = xt[pix][ (c*8+cl)*4 ..+4 )  (full 128B line/row)
    float4 ctr[4];
    const float4* cp = (const float4*)(xt + (size_t)pix * CH) + cl;
#pragma unroll
    for (int c = 0; c < 4; c++) ctr[c] = cp[c * 8];
    const float rnp = rn[pix];
    __syncthreads();                              // gnbl/mml ready

    // sims: 11 iterations, each handling TWO offsets (kb+g8, kb+8+g8).
    // All 8 loads issued before either reduce; two independent shfl chains.
    for (int kb = 0; kb < 176; kb += 16) {
        const int ka = kb + g8;                   // always < 169
        const int kc = kb + 8 + g8;               // may exceed 168
        const int ra = ka / 13, ca_ = ka - ra * 13;
        const int rc_ = kc / 13, cc_ = kc - rc_ * 13;
        const int pa = bb + refl(h + ra - 6) * WW + refl(w + ca_ - 6);
        const int pc = bb + refl(h + rc_ - 6) * WW + refl(w + cc_ - 6);
        const float4* rpa = (const float4*)(xt + (size_t)pa * CH) + cl;
        const float4* rpc = (const float4*)(xt + (size_t)pc * CH) + cl;
        float4 va0 = rpa[0],  va1 = rpa[8],  va2 = rpa[16], va3 = rpa[24];
        float4 vc0 = rpc[0],  vc1 = rpc[8],  vc2 = rpc[16], vc3 = rpc[24];
        float rna = rn[pa], rnc2 = rn[pc];
        float da = va0.x * ctr[0].x + va0.y * ctr[0].y + va0.z * ctr[0].z + va0.w * ctr[0].w
                 + va1.x * ctr[1].x + va1.y * ctr[1].y + va1.z * ctr[1].z + va1.w * ctr[1].w
                 + va2.x * ctr[2].x + va2.y * ctr[2].y + va2.z * ctr[2].z + va2.w * ctr[2].w
                 + va3.x * ctr[3].x + va3.y * ctr[3].y + va3.z * ctr[3].z + va3.w * ctr[3].w;
        float dc = vc0.x * ctr[0].x + vc0.y * ctr[0].y + vc0.z * ctr[0].z + vc0.w * ctr[0].w
                 + vc1.x * ctr[1].x + vc1.y * ctr[1].y + vc1.z * ctr[1].z + vc1.w * ctr[1].w
                 + vc2.x * ctr[2].x + vc2.y * ctr[2].y + vc2.z * ctr[2].z + vc2.w * ctr[2].w
                 + vc3.x * ctr[3].x + vc3.y * ctr[3].y + vc3.z * ctr[3].z + vc3.w * ctr[3].w;
        da += __shfl_xor(da, 1); dc += __shfl_xor(dc, 1);
        da += __shfl_xor(da, 2); dc += __shfl_xor(dc, 2);
        da += __shfl_xor(da, 4); dc += __shfl_xor(dc, 4);
        if (cl == 0) {
            sm.a.sims[wv][ka] = da * rnp * rna;
            if (kc < K2) sm.a.sims[wv][kc] = dc * rnp * rnc2;
        }
    }

    // own slots (same-wave LDS, no barrier needed)
    float s0 = sm.a.sims[wv][lane];
    float s1 = sm.a.sims[wv][64 + lane];          // 64+63=127 < 169: all valid
    float s2 = (128 + lane < K2) ? sm.a.sims[wv][128 + lane] : -1e30f;
    if (lane < 16) { sm.a.kl[wv][lane] = 0; sm.a.wl[wv][lane] = -1e30f; }

    const float dmin = mml[0], dmax = mml[1];
    const float dn = (df[pix] - dmin) / (dmax - dmin + 1e-8f);
    const int cc = 1 + (int)rintf(dn * 15.f);

    // extraction: record top-cc (value desc, index asc) into kl/wl only
    for (int i = 0; i < cc; ++i) {
        float gm = fmaxf(fmaxf(s0, s1), s2);
#pragma unroll
        for (int sft = 1; sft <= 32; sft <<= 1) gm = fmaxf(gm, __shfl_xor(gm, sft));
        unsigned long long m0 = __ballot(s0 == gm);
        unsigned long long m1 = __ballot(s1 == gm);
        unsigned long long m2 = __ballot(s2 == gm);
        int kw = m0 ? (__ffsll(m0) - 1)
               : m1 ? (64 + __ffsll(m1) - 1)
                    : (128 + __ffsll(m2) - 1);
        bool me = (lane == (kw & 63));
        s0 = (me && kw < 64) ? -1e30f : s0;
        s1 = (me && kw >= 64 && kw < 128) ? -1e30f : s1;
        s2 = (me && kw >= 128) ? -1e30f : s2;
        if (lane == 0) { sm.a.kl[wv][i] = kw; sm.a.wl[wv][i] = gm; }
    }

    // pipelined gather: 16 unrolled iterations, all loads in flight.
    // i >= cc: wl = -1e30 -> expf = 0 exactly; kl = 0 -> harmless load.
    float wsum = 0.f, ax = 0.f, ay = 0.f;
#pragma unroll
    for (int i = 0; i < 16; ++i) {
        const int kw = sm.a.kl[wv][i];
        const float sv = sm.a.wl[wv][i];
        const float wt = expf(sv);
        const int krow = kw / 13, kcol = kw - krow * 13;
        const int p2 = bb + refl(h + krow - 6) * WW + refl(w + kcol - 6);
        float2 v = ((const float2*)(xt + (size_t)p2 * CH))[lane];
        wsum += wt; ax += wt * v.x; ay += wt * v.y;
    }
    const float invw = 1.f / wsum;

    // GroupNorm + residual -> enhanced (registers)
    float2 xv = ((const float2*)(xt + (size_t)pix * CH))[lane];
    const int c0 = lane * 2, grp = lane >> 1;
    const float mu = gnbl[grp][0], rstd = gnbl[grp][1];
    float e0 = ax * invw + (xv.x - mu) * rstd * gamma[c0] + beta[c0];
    float e1 = ay * invw + (xv.y - mu) * rstd * gamma[c0 + 1] + beta[c0 + 1];

    __syncthreads();                              // all reads of sm.a done
    ((float2*)sm.f.elds[wv])[lane] = make_float2(e0, e1);
    __syncthreads();

    // FFN stage 1: thread = output o; 8-deep weight preload (8 loads in flight)
    {
        float acc4[4] = {0.f, 0.f, 0.f, 0.f};
        const float4* wp = ((const float4*)w1t) + tid;
        for (int c8 = 0; c8 < 4; c8++) {
            float4 wbuf[8];
#pragma unroll
            for (int j = 0; j < 8; j++) wbuf[j] = wp[(c8 * 8 + j) * 256];
#pragma unroll
            for (int j = 0; j < 8; j++) {
                const int c4 = c8 * 8 + j;
#pragma unroll
                for (int px = 0; px < 4; px++) {
                    float4 ev = *(const float4*)&sm.f.elds[px][c4 * 4];
                    acc4[px] += wbuf[j].x * ev.x + wbuf[j].y * ev.y +
                                wbuf[j].z * ev.z + wbuf[j].w * ev.w;
                }
            }
        }
        float bv = b1f[tid];
#pragma unroll
        for (int px = 0; px < 4; px++)
            sm.f.hlds[px][tid] = fmaxf(acc4[px] + bv, 0.f);
    }
    __syncthreads();
    // FFN stage 2 + residual: thread = (c, hf); 8-deep weight preload
    {
        const int c = tid & 127, hf = tid >> 7;
        const int px0 = hf * 2;
        float acc2[2] = {0.f, 0.f};
        const float4* wp2 = ((const float4*)w2t) + c;
        for (int o8 = 0; o8 < 8; o8++) {
            float4 wbuf[8];
#pragma unroll
            for (int j = 0; j < 8; j++) wbuf[j] = wp2[(o8 * 8 + j) * 128];
#pragma unroll
            for (int j = 0; j < 8; j++) {
                const int o4 = o8 * 8 + j;
#pragma unroll
                for (int jj = 0; jj < 2; jj++) {
                    float4 hv = *(const float4*)&sm.f.hlds[px0 + jj][o4 * 4];
                    acc2[jj] += wbuf[j].x * hv.x + wbuf[j].y * hv.y +
                                wbuf[j].z * hv.z + wbuf[j].w * hv.w;
                }
            }
        }
        float bv = b2f[c];
        float2 o2;
        o2.x = sm.f.elds[px0 + 0][c] + acc2[0] + bv;
        o2.y = sm.f.elds[px0 + 1][c] + acc2[1] + bv;
        *(float2*)(out + ((size_t)(b * CH + c)) * PP + (base % PP) + px0) = o2;
    }
}

extern "C" void kernel_launch(void* const* d_in, const int* in_sizes, int n_in,
                              void* d_out, int out_size, void* d_ws, size_t ws_size,
                              hipStream_t stream) {
    (void)in_sizes; (void)n_in; (void)out_size;
    if (ws_size < WS_FLOATS * sizeof(float)) return;  // would corrupt; fail visibly

    const float* x     = (const float*)d_in[0];
    const float* gamma = (const float*)d_in[1];
    const float* beta  = (const float*)d_in[2];
    const float* w1    = (const float*)d_in[3];
    const float* b1    = (const float*)d_in[4];
    const float* w2    = (const float*)d_in[5];
    const float* b2    = (const float*)d_in[6];
    float* ws = (float*)d_ws;
    float* xt  = ws + OFF_XT;
    float* rn  = ws + OFF_RN;
    float* df  = ws + OFF_DF;
    float* gnp = ws + OFF_GNP;
    float* mmp = ws + OFF_MMP;
    float* w1t = ws + OFF_W1T;
    float* w2t = ws + OFF_W2T;
    float* out = (float*)d_out;

    hipLaunchKernelGGL(kA, dim3(616),  dim3(256), 0, stream,
                       x, w1, w2, xt, gnp, w1t, w2t, df, rn, mmp);
    hipLaunchKernelGGL(kB, dim3(1152), dim3(256), 0, stream,
                       xt, rn, df, mmp, gnp, gamma, beta, w1t, w2t, b1, b2, out);
}